// Round 21
// baseline (201.281 us; speedup 1.0000x reference)
//
#include <hip/hip_runtime.h>
#include <hip/hip_fp16.h>
#include <stdint.h>

#define K_DIM 4096
#define N_OUT 4096
#define BM 256
#define BN 256
#define BKB 64  // K-bytes per step = 2 MFMA K-slices

typedef __attribute__((ext_vector_type(4))) int int32x4;
typedef __attribute__((ext_vector_type(16))) int int32x16;

// ------------- fused prologue: per-token quant (blocks < M) + weight pack ---
// quant: x_scale = max(x_max/7, fp16(1e-5)); x_q = clip(rint(x/x_scale),-8,7)
//        (all f32, no intermediate fp16 rounding — matches np reference).
// pack:  int32 -> int8 FRAGMENT-MAJOR wqf: block b = nfrag*128 + kslice,
//        each block 1024B in MFMA lane order.
__global__ __launch_bounds__(256) void quant_pack(
    const float* __restrict__ x, const int* __restrict__ w,
    int8_t* __restrict__ xq, float* __restrict__ xs,
    uint32_t* __restrict__ wqf, int M) {
  __shared__ float wmax[4];
  const int t = threadIdx.x;
  if ((int)blockIdx.x < M) {
    const int row = blockIdx.x;
    const float4* xr = (const float4*)(x + (size_t)row * K_DIM);
    float4 v[4];
    float m = 0.f;
#pragma unroll
    for (int i = 0; i < 4; ++i) {
      v[i] = xr[t * 4 + i];
      m = fmaxf(m, fmaxf(fmaxf(fabsf(v[i].x), fabsf(v[i].y)),
                         fmaxf(fabsf(v[i].z), fabsf(v[i].w))));
    }
#pragma unroll
    for (int off = 32; off > 0; off >>= 1) m = fmaxf(m, __shfl_xor(m, off));
    if ((t & 63) == 0) wmax[t >> 6] = m;
    __syncthreads();
    m = fmaxf(fmaxf(wmax[0], wmax[1]), fmaxf(wmax[2], wmax[3]));

    const float eps = 1.0013580322265625e-05f;  // fp16(1e-5) as f32
    const float xscale = fmaxf(m / 7.0f, eps);
    if (t == 0) xs[row] = xscale;

    uint32_t p[4];
#pragma unroll
    for (int g = 0; g < 4; ++g) {
      const float* fv = (const float*)&v[g];
      uint32_t wd = 0;
#pragma unroll
      for (int j = 0; j < 4; ++j) {
        float r = rintf(fv[j] / xscale);
        r = fminf(fmaxf(r, -8.f), 7.f);
        wd |= ((uint32_t)(uint8_t)(int8_t)(int)r) << (8 * j);
      }
      p[g] = wd;
    }
    *(uint4*)(xq + (size_t)row * K_DIM + t * 16) = *(uint4*)p;
  } else {
    const int c = (blockIdx.x - M) * 256 + t;  // one thread per 16B chunk
    const int blk = c >> 6;
    const int l = c & 63;
    const int row = ((blk >> 7) << 5) + (l & 31);
    const int k = ((blk & 127) << 5) + ((l >> 5) << 4);
    const int4* src = (const int4*)(w + (size_t)row * K_DIM + k);  // 16 ints
    uint32_t p[4];
#pragma unroll
    for (int g = 0; g < 4; ++g) {
      const int4 v = src[g];
      p[g] = (uint32_t)(v.x & 255) | ((uint32_t)(v.y & 255) << 8) |
             ((uint32_t)(v.z & 255) << 16) | ((uint32_t)(v.w & 255) << 24);
    }
    *(uint4*)(wqf + (size_t)c * 4) = *(uint4*)p;
  }
}

// ---------------- i8 GEMM: out = dequant(xq . wq^T) ----------------
// r21 = r20 (139us, 46.2%) with P2's reads HOISTED to the step top and the
// clusters gated by COUNTED lgkmcnt:
//   {12 ds_read (a x4, b x4, then c x4) | 4 staging glds | BARRIER |
//    lgkmcnt(4)+schedbar -> setprio + 8 MFMA (a,b) + setprio | BARRIER |
//    lgkmcnt(0)+schedbar -> setprio + 8 MFMA (c,b) + setprio |
//    vmcnt(4) | BARRIER}
// c's 384-cyc LDS service (prev. serialized between clusters) now rides
// under cluster 1's 586-cyc MFMA window; one barrier dropped (4 -> 3/step).
// DS ops retire in order per wave: lgkmcnt(4) = oldest 8 (a,b) done exactly.
// vmcnt(4) retires stage(s+1); stage(s+2) stays in flight (never 0 in loop).
// 4-deep LDS, compile-time rotation (u = s&3), 2-ahead staging as r20.
__global__ __launch_bounds__(512, 2) void gemm_w4a4(
    const int8_t* __restrict__ xq, const uint8_t* __restrict__ wqf,
    const float* __restrict__ xs, const float* __restrict__ wscale,
    float* __restrict__ out, int M) {
  __shared__ uint8_t lds[4][32768];  // [buf][A: 16 blk x 1KB | B: 16 blk x 1KB]

  // Swizzle (validated r8): A-panels XCD-exclusive, L2-resident.
  const int bid = blockIdx.x;
  const int xcd = bid & 7;
  const int i_loc = bid >> 3;            // 0..63
  const int mt = xcd * 4 + (i_loc & 3);  // 0..31, XCD-exclusive
  const int nt = i_loc >> 2;             // 0..15
  const int tm = mt * BM;
  const int tn = nt * BN;

  const int t = threadIdx.x;  // 0..511
  const int l = t & 63;
  const int wv = t >> 6;      // 0..7
  const int wm = wv >> 2;     // 0..1
  const int wn = wv & 3;      // 0..3

  // A staging source (validated lane map): row (l&31), k-chunk (l>>5)*16
  const uint8_t* gA = (const uint8_t*)xq +
                      (size_t)(tm + wv * 32 + (l & 31)) * K_DIM +
                      ((l >> 5) << 4);
  // B staging source: frag-major wqf, wave wv stages nfrag (nt*8+wv)
  const uint8_t* gB = wqf + (size_t)(nt * 8 + wv) * 131072 + (size_t)l * 16;

  int32x16 acc[4][2] = {};

  // stage A of step ss into buf: blocks (fa=wv, ks=j) at (wv*2+j)*1024
  auto stageA2 = [&](int buf, int ss) {
#pragma unroll
    for (int j = 0; j < 2; ++j) {
      __builtin_amdgcn_global_load_lds(
          (const __attribute__((address_space(1))) uint32_t*)(
              gA + ss * BKB + j * 32),
          (__attribute__((address_space(3))) uint32_t*)(
              &lds[buf][(wv * 2 + j) * 1024 + l * 16]),
          16, 0, 0);
    }
  };
  // stage B of step ss into buf: kslices (ss*2+j) -> 16384 + (wv*2+j)*1024
  auto stageB2 = [&](int buf, int ss) {
#pragma unroll
    for (int j = 0; j < 2; ++j) {
      __builtin_amdgcn_global_load_lds(
          (const __attribute__((address_space(1))) uint32_t*)(
              gB + ((size_t)(ss * 2 + j) << 10)),
          (__attribute__((address_space(3))) uint32_t*)(
              &lds[buf][16384 + (wv * 2 + j) * 1024 + l * 16]),
          16, 0, 0);
    }
  };

  // prologue: stage steps 0 (buf0) and 1 (buf1); retire step-0's 4 glds
  stageA2(0, 0);
  stageB2(0, 0);
  stageA2(1, 1);
  stageB2(1, 1);
  asm volatile("s_waitcnt vmcnt(4)" ::: "memory");
  __builtin_amdgcn_s_barrier();

  for (int su = 0; su < 16; ++su) {  // 64 steps = 16 x 4 (buf compile-time)
#pragma unroll
    for (int u = 0; u < 4; ++u) {
      const int s = su * 4 + u;
      const int sbuf = (u + 2) & 3;      // compile-time
      const int ss = (s + 2) & 63;       // wrapped; tail writes dead buffers
      const uint8_t* aB = &lds[u][wm * 8192 + l * 16];
      const uint8_t* bB = &lds[u][16384 + wn * 4096 + l * 16];

      // ---- step top: ALL 12 ds_reads (a,b first, c last) + 4 staging ----
      int32x4 a[2][2], b[2][2], c[2][2];  // [m][ks], [n][ks], [m+2][ks]
#pragma unroll
      for (int m = 0; m < 2; ++m)
#pragma unroll
        for (int ks = 0; ks < 2; ++ks)
          a[m][ks] = *(const int32x4*)(aB + m * 2048 + ks * 1024);
#pragma unroll
      for (int n = 0; n < 2; ++n)
#pragma unroll
        for (int ks = 0; ks < 2; ++ks)
          b[n][ks] = *(const int32x4*)(bB + n * 2048 + ks * 1024);
#pragma unroll
      for (int m = 0; m < 2; ++m)
#pragma unroll
        for (int ks = 0; ks < 2; ++ks)
          c[m][ks] = *(const int32x4*)(aB + (2 + m) * 2048 + ks * 1024);
      stageA2(sbuf, ss);
      stageB2(sbuf, ss);

      // ---- cluster 1: m0,m1 (a,b ready via counted lgkm; c in flight) ----
      __builtin_amdgcn_s_barrier();
      asm volatile("s_waitcnt lgkmcnt(4)" ::: "memory");
      __builtin_amdgcn_sched_barrier(0);
      __builtin_amdgcn_s_setprio(1);
#pragma unroll
      for (int ks = 0; ks < 2; ++ks)
#pragma unroll
        for (int m = 0; m < 2; ++m)
#pragma unroll
          for (int n = 0; n < 2; ++n)
            acc[m][n] = __builtin_amdgcn_mfma_i32_32x32x32_i8(
                a[m][ks], b[n][ks], acc[m][n], 0, 0, 0);
      __builtin_amdgcn_s_setprio(0);
      __builtin_amdgcn_s_barrier();

      // ---- cluster 2: m2,m3 (c landed under cluster 1; b reused) ----
      asm volatile("s_waitcnt lgkmcnt(0)" ::: "memory");
      __builtin_amdgcn_sched_barrier(0);
      __builtin_amdgcn_s_setprio(1);
#pragma unroll
      for (int ks = 0; ks < 2; ++ks)
#pragma unroll
        for (int m = 0; m < 2; ++m)
#pragma unroll
          for (int n = 0; n < 2; ++n)
            acc[2 + m][n] = __builtin_amdgcn_mfma_i32_32x32x32_i8(
                c[m][ks], b[n][ks], acc[2 + m][n], 0, 0, 0);
      __builtin_amdgcn_s_setprio(0);
      // retire step-(s+1)'s 4 glds; step-(s+2)'s stay in flight
      asm volatile("s_waitcnt vmcnt(4)" ::: "memory");
      __builtin_amdgcn_s_barrier();
    }
  }
  asm volatile("s_waitcnt vmcnt(0)" ::: "memory");  // drain dead prefetches

  // epilogue: dequant + fp16-round, write f32
  const int colbase = tn + wn * 64;
  const int rowbase = tm + wm * 128 + 4 * (l >> 5);
#pragma unroll
  for (int m = 0; m < 4; ++m) {
#pragma unroll
    for (int n = 0; n < 2; ++n) {
      const int col = colbase + n * 32 + (l & 31);
      const float wsc = wscale[col];
#pragma unroll
      for (int j = 0; j < 16; ++j) {
        const int row = rowbase + m * 32 + (j & 3) + 8 * (j >> 2);
        const float val = (float)acc[m][n][j] * (xs[row] * wsc);
        out[(size_t)row * N_OUT + col] = __half2float(__float2half(val));
      }
    }
  }
}

extern "C" void kernel_launch(void* const* d_in, const int* in_sizes, int n_in,
                              void* d_out, int out_size, void* d_ws, size_t ws_size,
                              hipStream_t stream) {
  const float* x = (const float*)d_in[0];    // fp16 values as f32
  const int* w = (const int*)d_in[1];        // int4-range values as i32
  const float* wsc = (const float*)d_in[2];  // fp16 values as f32
  float* out = (float*)d_out;

  const int M = in_sizes[0] / K_DIM;  // 8192 tokens

  uint8_t* ws = (uint8_t*)d_ws;
  int8_t* xq = (int8_t*)ws;                              // M*K bytes
  uint8_t* wqf = ws + (size_t)M * K_DIM;                 // N*K bytes (frag-major)
  float* xs = (float*)(ws + (size_t)M * K_DIM + (size_t)N_OUT * K_DIM);

  const int packBlocks = N_OUT * K_DIM / 16 / 256;  // 4096
  quant_pack<<<M + packBlocks, 256, 0, stream>>>(x, w, xq, xs,
                                                 (uint32_t*)wqf, M);
  gemm_w4a4<<<(M / BM) * (N_OUT / BN), 512, 0, stream>>>(
      xq, wqf, xs, wsc, out, M);
}

// Round 22
// 189.399 us; speedup vs baseline: 1.0627x; 1.0627x over previous
//
#include <hip/hip_runtime.h>
#include <hip/hip_fp16.h>
#include <stdint.h>

#define K_DIM 4096
#define N_OUT 4096
#define BM 256
#define BN 256
#define BKB 64  // K-bytes per step = 2 MFMA K-slices

typedef __attribute__((ext_vector_type(4))) int int32x4;
typedef __attribute__((ext_vector_type(16))) int int32x16;

// ------------- fused prologue: per-token quant (blocks < M) + weight pack ---
// quant: x_scale = max(x_max/7, fp16(1e-5)); x_q = clip(rint(x/x_scale),-8,7)
//        (all f32, no intermediate fp16 rounding — matches np reference).
// pack:  int32 -> int8 FRAGMENT-MAJOR wqf: block b = nfrag*128 + kslice,
//        each block 1024B in MFMA lane order.
__global__ __launch_bounds__(256) void quant_pack(
    const float* __restrict__ x, const int* __restrict__ w,
    int8_t* __restrict__ xq, float* __restrict__ xs,
    uint32_t* __restrict__ wqf, int M) {
  __shared__ float wmax[4];
  const int t = threadIdx.x;
  if ((int)blockIdx.x < M) {
    const int row = blockIdx.x;
    const float4* xr = (const float4*)(x + (size_t)row * K_DIM);
    float4 v[4];
    float m = 0.f;
#pragma unroll
    for (int i = 0; i < 4; ++i) {
      v[i] = xr[t * 4 + i];
      m = fmaxf(m, fmaxf(fmaxf(fabsf(v[i].x), fabsf(v[i].y)),
                         fmaxf(fabsf(v[i].z), fabsf(v[i].w))));
    }
#pragma unroll
    for (int off = 32; off > 0; off >>= 1) m = fmaxf(m, __shfl_xor(m, off));
    if ((t & 63) == 0) wmax[t >> 6] = m;
    __syncthreads();
    m = fmaxf(fmaxf(wmax[0], wmax[1]), fmaxf(wmax[2], wmax[3]));

    const float eps = 1.0013580322265625e-05f;  // fp16(1e-5) as f32
    const float xscale = fmaxf(m / 7.0f, eps);
    if (t == 0) xs[row] = xscale;

    uint32_t p[4];
#pragma unroll
    for (int g = 0; g < 4; ++g) {
      const float* fv = (const float*)&v[g];
      uint32_t wd = 0;
#pragma unroll
      for (int j = 0; j < 4; ++j) {
        float r = rintf(fv[j] / xscale);
        r = fminf(fmaxf(r, -8.f), 7.f);
        wd |= ((uint32_t)(uint8_t)(int8_t)(int)r) << (8 * j);
      }
      p[g] = wd;
    }
    *(uint4*)(xq + (size_t)row * K_DIM + t * 16) = *(uint4*)p;
  } else {
    const int c = (blockIdx.x - M) * 256 + t;  // one thread per 16B chunk
    const int blk = c >> 6;
    const int l = c & 63;
    const int row = ((blk >> 7) << 5) + (l & 31);
    const int k = ((blk & 127) << 5) + ((l >> 5) << 4);
    const int4* src = (const int4*)(w + (size_t)row * K_DIM + k);  // 16 ints
    uint32_t p[4];
#pragma unroll
    for (int g = 0; g < 4; ++g) {
      const int4 v = src[g];
      p[g] = (uint32_t)(v.x & 255) | ((uint32_t)(v.y & 255) << 8) |
             ((uint32_t)(v.z & 255) << 16) | ((uint32_t)(v.w & 255) << 24);
    }
    *(uint4*)(wqf + (size_t)c * 4) = *(uint4*)p;
  }
}

// ---------------- i8 GEMM: out = dequant(xq . wq^T) ----------------
// r22 = r20 (best: 139us, 46.2%) with ONE change: P2's c-reads (A frags
// m2,m3) are issued INSIDE cluster 1's MFMA window — right after cluster 1's
// lgkmcnt(0) gate (cluster 1 doesn't depend on c), pinned before the MFMAs
// by sched_barrier(0). Their 385-cyc CU-wide LDS service rides under the
// 586-cyc MFMA cluster instead of sitting serialized between clusters
// (r21's mistake: hoisting them BEFORE cluster 1 just grew the lockstep
// pre-cluster burst). P2 keeps its barrier structure; its lgkm(0) now waits
// c (already landed). All 4 barriers, vmcnt(4) ledger, 4-deep compile-time
// LDS rotation, 2-ahead staging — identical to r20.
__global__ __launch_bounds__(512, 2) void gemm_w4a4(
    const int8_t* __restrict__ xq, const uint8_t* __restrict__ wqf,
    const float* __restrict__ xs, const float* __restrict__ wscale,
    float* __restrict__ out, int M) {
  __shared__ uint8_t lds[4][32768];  // [buf][A: 16 blk x 1KB | B: 16 blk x 1KB]

  // Swizzle (validated r8): A-panels XCD-exclusive, L2-resident.
  const int bid = blockIdx.x;
  const int xcd = bid & 7;
  const int i_loc = bid >> 3;            // 0..63
  const int mt = xcd * 4 + (i_loc & 3);  // 0..31, XCD-exclusive
  const int nt = i_loc >> 2;             // 0..15
  const int tm = mt * BM;
  const int tn = nt * BN;

  const int t = threadIdx.x;  // 0..511
  const int l = t & 63;
  const int wv = t >> 6;      // 0..7
  const int wm = wv >> 2;     // 0..1
  const int wn = wv & 3;      // 0..3

  // A staging source (validated lane map): row (l&31), k-chunk (l>>5)*16
  const uint8_t* gA = (const uint8_t*)xq +
                      (size_t)(tm + wv * 32 + (l & 31)) * K_DIM +
                      ((l >> 5) << 4);
  // B staging source: frag-major wqf, wave wv stages nfrag (nt*8+wv)
  const uint8_t* gB = wqf + (size_t)(nt * 8 + wv) * 131072 + (size_t)l * 16;

  int32x16 acc[4][2] = {};

  // stage A of step ss into buf: blocks (fa=wv, ks=j) at (wv*2+j)*1024
  auto stageA2 = [&](int buf, int ss) {
#pragma unroll
    for (int j = 0; j < 2; ++j) {
      __builtin_amdgcn_global_load_lds(
          (const __attribute__((address_space(1))) uint32_t*)(
              gA + ss * BKB + j * 32),
          (__attribute__((address_space(3))) uint32_t*)(
              &lds[buf][(wv * 2 + j) * 1024 + l * 16]),
          16, 0, 0);
    }
  };
  // stage B of step ss into buf: kslices (ss*2+j) -> 16384 + (wv*2+j)*1024
  auto stageB2 = [&](int buf, int ss) {
#pragma unroll
    for (int j = 0; j < 2; ++j) {
      __builtin_amdgcn_global_load_lds(
          (const __attribute__((address_space(1))) uint32_t*)(
              gB + ((size_t)(ss * 2 + j) << 10)),
          (__attribute__((address_space(3))) uint32_t*)(
              &lds[buf][16384 + (wv * 2 + j) * 1024 + l * 16]),
          16, 0, 0);
    }
  };

  // prologue: stage steps 0 (buf0) and 1 (buf1); retire step-0's 4 glds
  stageA2(0, 0);
  stageB2(0, 0);
  stageA2(1, 1);
  stageB2(1, 1);
  asm volatile("s_waitcnt vmcnt(4)" ::: "memory");
  __builtin_amdgcn_s_barrier();

  for (int su = 0; su < 16; ++su) {  // 64 steps = 16 x 4 (buf compile-time)
#pragma unroll
    for (int u = 0; u < 4; ++u) {
      const int s = su * 4 + u;
      const int sbuf = (u + 2) & 3;      // compile-time
      const int ss = (s + 2) & 63;       // wrapped; tail writes dead buffers
      const uint8_t* aB = &lds[u][wm * 8192 + l * 16];
      const uint8_t* bB = &lds[u][16384 + wn * 4096 + l * 16];

      // ---- Phase 1: reads a,b + stageA ----
      int32x4 a[2][2], b[2][2], c[2][2];  // [m][ks], [n][ks], [m+2][ks]
#pragma unroll
      for (int m = 0; m < 2; ++m)
#pragma unroll
        for (int ks = 0; ks < 2; ++ks)
          a[m][ks] = *(const int32x4*)(aB + m * 2048 + ks * 1024);
#pragma unroll
      for (int n = 0; n < 2; ++n)
#pragma unroll
        for (int ks = 0; ks < 2; ++ks)
          b[n][ks] = *(const int32x4*)(bB + n * 2048 + ks * 1024);
      stageA2(sbuf, ss);

      // ---- cluster 1 (m0,m1): c-reads issued INSIDE the MFMA window ----
      __builtin_amdgcn_s_barrier();
      asm volatile("s_waitcnt lgkmcnt(0)" ::: "memory");
      __builtin_amdgcn_sched_barrier(0);
      __builtin_amdgcn_s_setprio(1);
#pragma unroll
      for (int m = 0; m < 2; ++m)
#pragma unroll
        for (int ks = 0; ks < 2; ++ks)
          c[m][ks] = *(const int32x4*)(aB + (2 + m) * 2048 + ks * 1024);
      __builtin_amdgcn_sched_barrier(0);  // pin c-issue before the MFMAs
#pragma unroll
      for (int ks = 0; ks < 2; ++ks)
#pragma unroll
        for (int m = 0; m < 2; ++m)
#pragma unroll
          for (int n = 0; n < 2; ++n)
            acc[m][n] = __builtin_amdgcn_mfma_i32_32x32x32_i8(
                a[m][ks], b[n][ks], acc[m][n], 0, 0, 0);
      __builtin_amdgcn_s_setprio(0);
      __builtin_amdgcn_s_barrier();

      // ---- Phase 2: stageB only (c already in flight / landed) ----
      stageB2(sbuf, ss);
      __builtin_amdgcn_s_barrier();
      asm volatile("s_waitcnt lgkmcnt(0)" ::: "memory");
      __builtin_amdgcn_sched_barrier(0);
      __builtin_amdgcn_s_setprio(1);
#pragma unroll
      for (int ks = 0; ks < 2; ++ks)
#pragma unroll
        for (int m = 0; m < 2; ++m)
#pragma unroll
          for (int n = 0; n < 2; ++n)
            acc[2 + m][n] = __builtin_amdgcn_mfma_i32_32x32x32_i8(
                c[m][ks], b[n][ks], acc[2 + m][n], 0, 0, 0);
      __builtin_amdgcn_s_setprio(0);
      // retire step-(s+1)'s 4 glds; step-(s+2)'s stay in flight
      asm volatile("s_waitcnt vmcnt(4)" ::: "memory");
      __builtin_amdgcn_s_barrier();
    }
  }
  asm volatile("s_waitcnt vmcnt(0)" ::: "memory");  // drain dead prefetches

  // epilogue: dequant + fp16-round, write f32
  const int colbase = tn + wn * 64;
  const int rowbase = tm + wm * 128 + 4 * (l >> 5);
#pragma unroll
  for (int m = 0; m < 4; ++m) {
#pragma unroll
    for (int n = 0; n < 2; ++n) {
      const int col = colbase + n * 32 + (l & 31);
      const float wsc = wscale[col];
#pragma unroll
      for (int j = 0; j < 16; ++j) {
        const int row = rowbase + m * 32 + (j & 3) + 8 * (j >> 2);
        const float val = (float)acc[m][n][j] * (xs[row] * wsc);
        out[(size_t)row * N_OUT + col] = __half2float(__float2half(val));
      }
    }
  }
}

extern "C" void kernel_launch(void* const* d_in, const int* in_sizes, int n_in,
                              void* d_out, int out_size, void* d_ws, size_t ws_size,
                              hipStream_t stream) {
  const float* x = (const float*)d_in[0];    // fp16 values as f32
  const int* w = (const int*)d_in[1];        // int4-range values as i32
  const float* wsc = (const float*)d_in[2];  // fp16 values as f32
  float* out = (float*)d_out;

  const int M = in_sizes[0] / K_DIM;  // 8192 tokens

  uint8_t* ws = (uint8_t*)d_ws;
  int8_t* xq = (int8_t*)ws;                              // M*K bytes
  uint8_t* wqf = ws + (size_t)M * K_DIM;                 // N*K bytes (frag-major)
  float* xs = (float*)(ws + (size_t)M * K_DIM + (size_t)N_OUT * K_DIM);

  const int packBlocks = N_OUT * K_DIM / 16 / 256;  // 4096
  quant_pack<<<M + packBlocks, 256, 0, stream>>>(x, w, xq, xs,
                                                 (uint32_t*)wqf, M);
  gemm_w4a4<<<(M / BM) * (N_OUT / BN), 512, 0, stream>>>(
      xq, wqf, xs, wsc, out, M);
}